// Round 1
// baseline (450.279 us; speedup 1.0000x reference)
//
#include <hip/hip_runtime.h>

#define HEADS 8
#define HD 16
#define HID 128   // HEADS * HD

// One edge is handled by 128 consecutive threads: t = h*16 + d.
// Dot product over the 16 dims of a head via shfl_xor reduction.
__global__ void edge_attn_kernel(const float* __restrict__ q,
                                 const float* __restrict__ k,
                                 const float* __restrict__ v,
                                 const int* __restrict__ ei,
                                 float* __restrict__ wV,   // [N*128], accumulated (= d_out)
                                 float* __restrict__ Z,    // [N*8]
                                 int E) {
    long long gid = (long long)blockIdx.x * blockDim.x + threadIdx.x;
    int edge = (int)(gid >> 7);
    int t = (int)(gid & 127);
    if (edge >= E) return;

    int src = ei[edge];
    int dst = ei[E + edge];

    float kv = k[(long long)src * HID + t];
    float qv = q[(long long)dst * HID + t];
    float p = kv * qv * 0.25f;   // / SCALE, SCALE = sqrt(16) = 4

    // reduce across the 16 lanes of this head (lanes share a 16-lane group)
    p += __shfl_xor(p, 1);
    p += __shfl_xor(p, 2);
    p += __shfl_xor(p, 4);
    p += __shfl_xor(p, 8);

    float s = fminf(fmaxf(p, -5.0f), 5.0f);
    float score = __expf(s);

    float msg = v[(long long)src * HID + t] * score;
    atomicAdd(&wV[(long long)dst * HID + t], msg);
    if ((t & 15) == 0) {
        atomicAdd(&Z[dst * HEADS + (t >> 4)], score);
    }
}

__global__ void finalize_kernel(float* __restrict__ out,
                                const float* __restrict__ Z,
                                int total) {
    int i = blockIdx.x * blockDim.x + threadIdx.x;
    if (i >= total) return;
    int node = i >> 7;        // /128
    int h = (i >> 4) & 7;     // head
    out[i] = out[i] / (Z[node * HEADS + h] + 1e-6f);
}

extern "C" void kernel_launch(void* const* d_in, const int* in_sizes, int n_in,
                              void* d_out, int out_size, void* d_ws, size_t ws_size,
                              hipStream_t stream) {
    const float* q = (const float*)d_in[0];
    const float* k = (const float*)d_in[1];
    const float* v = (const float*)d_in[2];
    const int* ei = (const int*)d_in[3];
    float* out = (float*)d_out;

    int E = in_sizes[3] / 2;          // 800000
    int N = in_sizes[0] / HID;        // 50000
    float* Z = (float*)d_ws;          // N*8 floats

    // zero accumulators (graph-capturable async memsets)
    hipMemsetAsync(out, 0, (size_t)out_size * sizeof(float), stream);
    hipMemsetAsync(Z, 0, (size_t)N * HEADS * sizeof(float), stream);

    // edge kernel: 128 threads/edge
    long long total_threads = (long long)E * HID;
    int block = 256;
    long long grid = (total_threads + block - 1) / block;
    edge_attn_kernel<<<(int)grid, block, 0, stream>>>(q, k, v, ei, out, Z, E);

    // finalize: out /= (Z + 1e-6)
    int fblock = 256;
    int fgrid = (out_size + fblock - 1) / fblock;
    finalize_kernel<<<fgrid, fblock, 0, stream>>>(out, Z, out_size);
}

// Round 2
// 278.123 us; speedup vs baseline: 1.6190x; 1.6190x over previous
//
#include <hip/hip_runtime.h>

#define HEADS 8
#define HD 16
#define HID 128
#define NODES_PER_BLOCK 4   // 4 nodes x 1 wave(64) per 256-thread block

// ---------------- CSR build ----------------

__global__ void count_kernel(const int* __restrict__ ei, int* __restrict__ counts, int E) {
    int e = blockIdx.x * blockDim.x + threadIdx.x;
    if (e < E) atomicAdd(&counts[ei[E + e]], 1);
}

// Single-block exclusive scan over counts[0..N) -> offsets[0..N], cursor copy.
// 1024 threads, 4 elements/thread/iteration (4096 per sweep).
__global__ void scan_kernel(const int* __restrict__ counts, int* __restrict__ offsets,
                            int* __restrict__ cursor, int N, int E) {
    __shared__ int sdata[1024];
    __shared__ int carry_s;
    int tid = threadIdx.x;
    if (tid == 0) carry_s = 0;
    __syncthreads();
    for (int base = 0; base < N; base += 4096) {
        int v[4];
        int tsum = 0;
        for (int j = 0; j < 4; j++) {
            int idx = base + tid * 4 + j;
            v[j] = (idx < N) ? counts[idx] : 0;
            tsum += v[j];
        }
        sdata[tid] = tsum;
        __syncthreads();
        for (int off = 1; off < 1024; off <<= 1) {
            int x = sdata[tid];
            int y = (tid >= off) ? sdata[tid - off] : 0;
            __syncthreads();
            sdata[tid] = x + y;
            __syncthreads();
        }
        int excl = sdata[tid] - tsum + carry_s;
        for (int j = 0; j < 4; j++) {
            int idx = base + tid * 4 + j;
            if (idx < N) { offsets[idx] = excl; cursor[idx] = excl; }
            excl += v[j];
        }
        __syncthreads();
        if (tid == 1023) carry_s += sdata[1023];
        __syncthreads();
    }
    if (tid == 0) offsets[N] = E;
}

__global__ void fill_kernel(const int* __restrict__ ei, int* __restrict__ cursor,
                            int* __restrict__ srcs, int E) {
    int e = blockIdx.x * blockDim.x + threadIdx.x;
    if (e < E) {
        int dst = ei[E + e];
        int pos = atomicAdd(&cursor[dst], 1);
        srcs[pos] = ei[e];
    }
}

// ---------------- per-node segmented reduction (atomic-free) ----------------
// One wave (64 lanes) per node; lane l handles dims [2l, 2l+1].
// Head h = l>>3 (8 lanes/head); dot reduced via shfl_xor 1,2,4 within 8-lane group.
__global__ __launch_bounds__(256) void reduce_kernel(
        const float* __restrict__ q, const float* __restrict__ k,
        const float* __restrict__ v, const int* __restrict__ offsets,
        const int* __restrict__ srcs, float* __restrict__ out, int N) {
    int node = blockIdx.x * NODES_PER_BLOCK + (threadIdx.x >> 6);
    if (node >= N) return;
    int l = threadIdx.x & 63;

    const float2* q2 = (const float2*)(q + (long long)node * HID);
    float2 qv = q2[l];
    float2 acc = make_float2(0.0f, 0.0f);
    float z = 0.0f;

    int beg = offsets[node];
    int end = offsets[node + 1];
    for (int i = beg; i < end; i++) {
        int src = srcs[i];
        const float2* k2 = (const float2*)(k + (long long)src * HID);
        const float2* v2 = (const float2*)(v + (long long)src * HID);
        float2 kv = k2[l];
        float2 vv = v2[l];
        float p = (kv.x * qv.x + kv.y * qv.y) * 0.25f;  // /SCALE, SCALE=4
        p += __shfl_xor(p, 1);
        p += __shfl_xor(p, 2);
        p += __shfl_xor(p, 4);
        float s = fminf(fmaxf(p, -5.0f), 5.0f);
        float score = __expf(s);
        acc.x += vv.x * score;
        acc.y += vv.y * score;
        z += score;   // identical across the 8 lanes of this head
    }
    float inv = 1.0f / (z + 1e-6f);
    float2* o2 = (float2*)(out + (long long)node * HID);
    o2[l] = make_float2(acc.x * inv, acc.y * inv);
}

extern "C" void kernel_launch(void* const* d_in, const int* in_sizes, int n_in,
                              void* d_out, int out_size, void* d_ws, size_t ws_size,
                              hipStream_t stream) {
    const float* q = (const float*)d_in[0];
    const float* k = (const float*)d_in[1];
    const float* v = (const float*)d_in[2];
    const int* ei = (const int*)d_in[3];
    float* out = (float*)d_out;

    int E = in_sizes[3] / 2;      // 800000
    int N = in_sizes[0] / HID;    // 50000

    // workspace layout (ints): counts[64K] | offsets[64K] | cursor[64K] | srcs[E]
    int* counts  = (int*)d_ws;
    int* offsets = counts + 65536;
    int* cursor  = offsets + 65536;
    int* srcs    = cursor + 65536;

    hipMemsetAsync(counts, 0, (size_t)N * sizeof(int), stream);

    int block = 256;
    int egrid = (E + block - 1) / block;
    count_kernel<<<egrid, block, 0, stream>>>(ei, counts, E);
    scan_kernel<<<1, 1024, 0, stream>>>(counts, offsets, cursor, N, E);
    fill_kernel<<<egrid, block, 0, stream>>>(ei, cursor, srcs, E);

    int rgrid = (N + NODES_PER_BLOCK - 1) / NODES_PER_BLOCK;
    reduce_kernel<<<rgrid, block, 0, stream>>>(q, k, v, offsets, srcs, out, N);
}

// Round 3
// 223.298 us; speedup vs baseline: 2.0165x; 1.2455x over previous
//
#include <hip/hip_runtime.h>

#define HEADS 8
#define HD 16
#define HID 128
#define NODES_PER_BLOCK 4   // 4 nodes x 1 wave(64) per 256-thread block

// ---------------- CSR build ----------------

__global__ void count_kernel(const int* __restrict__ ei, int* __restrict__ counts, int E) {
    int e = blockIdx.x * blockDim.x + threadIdx.x;
    if (e < E) atomicAdd(&counts[ei[E + e]], 1);
}

// Phase A: per-block (2048 elems) local exclusive scan + block totals.
__global__ void scanA_kernel(const int* __restrict__ counts, int* __restrict__ offsets,
                             int* __restrict__ partials, int N) {
    __shared__ int sdata[256];
    int tid = threadIdx.x;
    int base = blockIdx.x * 2048 + tid * 8;
    int v[8];
    int tsum = 0;
    for (int j = 0; j < 8; j++) {
        int idx = base + j;
        v[j] = (idx < N) ? counts[idx] : 0;
        tsum += v[j];
    }
    sdata[tid] = tsum;
    __syncthreads();
    for (int off = 1; off < 256; off <<= 1) {
        int x = sdata[tid];
        int y = (tid >= off) ? sdata[tid - off] : 0;
        __syncthreads();
        sdata[tid] = x + y;
        __syncthreads();
    }
    int excl = sdata[tid] - tsum;
    for (int j = 0; j < 8; j++) {
        int idx = base + j;
        if (idx < N) offsets[idx] = excl;
        excl += v[j];
    }
    if (tid == 255) partials[blockIdx.x] = sdata[255];
}

// Phase B: serial exclusive scan of the ~25 block totals (trivial).
__global__ void scanB_kernel(int* __restrict__ partials, int nb) {
    if (threadIdx.x == 0 && blockIdx.x == 0) {
        int run = 0;
        for (int i = 0; i < nb; i++) { int t = partials[i]; partials[i] = run; run += t; }
    }
}

// Phase C: add block base, copy to cursor, set offsets[N].
__global__ void scanC_kernel(int* __restrict__ offsets, int* __restrict__ cursor,
                             const int* __restrict__ partials, int N, int E) {
    int idx = blockIdx.x * blockDim.x + threadIdx.x;
    if (idx < N) {
        int o = offsets[idx] + partials[idx >> 11];  // 2048 elems per scanA block
        offsets[idx] = o;
        cursor[idx] = o;
    }
    if (idx == 0) offsets[N] = E;
}

__global__ void fill_kernel(const int* __restrict__ ei, int* __restrict__ cursor,
                            int* __restrict__ srcs, int E) {
    int e = blockIdx.x * blockDim.x + threadIdx.x;
    if (e < E) {
        int dst = ei[E + e];
        int pos = atomicAdd(&cursor[dst], 1);
        srcs[pos] = ei[e];
    }
}

// ---------------- per-node segmented reduction (atomic-free) ----------------
// One wave per node; lane l covers dims [2l,2l+1]; 8 lanes per head.
// 4-deep unroll: 8 independent 512B gathers in flight per wave.
__global__ __launch_bounds__(256) void reduce_kernel(
        const float* __restrict__ q, const float* __restrict__ k,
        const float* __restrict__ v, const int* __restrict__ offsets,
        const int* __restrict__ srcs, float* __restrict__ out, int N) {
    int node = blockIdx.x * NODES_PER_BLOCK + (threadIdx.x >> 6);
    if (node >= N) return;
    int l = threadIdx.x & 63;

    float2 qv = ((const float2*)(q + (long long)node * HID))[l];
    float accx = 0.0f, accy = 0.0f;
    float z = 0.0f;

    int beg = offsets[node];
    int end = offsets[node + 1];
    int i = beg;
    for (; i + 4 <= end; i += 4) {
        int s0 = srcs[i + 0], s1 = srcs[i + 1], s2 = srcs[i + 2], s3 = srcs[i + 3];
        float2 k0 = ((const float2*)(k + (long long)s0 * HID))[l];
        float2 k1 = ((const float2*)(k + (long long)s1 * HID))[l];
        float2 k2 = ((const float2*)(k + (long long)s2 * HID))[l];
        float2 k3 = ((const float2*)(k + (long long)s3 * HID))[l];
        float2 v0 = ((const float2*)(v + (long long)s0 * HID))[l];
        float2 v1 = ((const float2*)(v + (long long)s1 * HID))[l];
        float2 v2 = ((const float2*)(v + (long long)s2 * HID))[l];
        float2 v3 = ((const float2*)(v + (long long)s3 * HID))[l];

        float p0 = (k0.x * qv.x + k0.y * qv.y) * 0.25f;
        float p1 = (k1.x * qv.x + k1.y * qv.y) * 0.25f;
        float p2 = (k2.x * qv.x + k2.y * qv.y) * 0.25f;
        float p3 = (k3.x * qv.x + k3.y * qv.y) * 0.25f;

        p0 += __shfl_xor(p0, 1); p1 += __shfl_xor(p1, 1);
        p2 += __shfl_xor(p2, 1); p3 += __shfl_xor(p3, 1);
        p0 += __shfl_xor(p0, 2); p1 += __shfl_xor(p1, 2);
        p2 += __shfl_xor(p2, 2); p3 += __shfl_xor(p3, 2);
        p0 += __shfl_xor(p0, 4); p1 += __shfl_xor(p1, 4);
        p2 += __shfl_xor(p2, 4); p3 += __shfl_xor(p3, 4);

        float c0 = __expf(fminf(fmaxf(p0, -5.0f), 5.0f));
        float c1 = __expf(fminf(fmaxf(p1, -5.0f), 5.0f));
        float c2 = __expf(fminf(fmaxf(p2, -5.0f), 5.0f));
        float c3 = __expf(fminf(fmaxf(p3, -5.0f), 5.0f));

        accx += v0.x * c0 + v1.x * c1 + v2.x * c2 + v3.x * c3;
        accy += v0.y * c0 + v1.y * c1 + v2.y * c2 + v3.y * c3;
        z += c0 + c1 + c2 + c3;
    }
    for (; i < end; i++) {
        int s = srcs[i];
        float2 kv = ((const float2*)(k + (long long)s * HID))[l];
        float2 vv = ((const float2*)(v + (long long)s * HID))[l];
        float p = (kv.x * qv.x + kv.y * qv.y) * 0.25f;
        p += __shfl_xor(p, 1);
        p += __shfl_xor(p, 2);
        p += __shfl_xor(p, 4);
        float c = __expf(fminf(fmaxf(p, -5.0f), 5.0f));
        accx += vv.x * c;
        accy += vv.y * c;
        z += c;
    }
    float inv = 1.0f / (z + 1e-6f);
    ((float2*)(out + (long long)node * HID))[l] = make_float2(accx * inv, accy * inv);
}

extern "C" void kernel_launch(void* const* d_in, const int* in_sizes, int n_in,
                              void* d_out, int out_size, void* d_ws, size_t ws_size,
                              hipStream_t stream) {
    const float* q = (const float*)d_in[0];
    const float* k = (const float*)d_in[1];
    const float* v = (const float*)d_in[2];
    const int* ei = (const int*)d_in[3];
    float* out = (float*)d_out;

    int E = in_sizes[3] / 2;      // 800000
    int N = in_sizes[0] / HID;    // 50000

    // workspace (ints): counts[64K] | offsets[64K+1 pad to 64K+256] | cursor[64K] | partials[256] | srcs[E]
    int* counts   = (int*)d_ws;
    int* offsets  = counts + 65536;
    int* cursor   = offsets + 65536 + 256;
    int* partials = cursor + 65536;
    int* srcs     = partials + 256;

    hipMemsetAsync(counts, 0, (size_t)N * sizeof(int), stream);

    int block = 256;
    int egrid = (E + block - 1) / block;
    count_kernel<<<egrid, block, 0, stream>>>(ei, counts, E);

    int nbA = (N + 2047) / 2048;   // 25
    scanA_kernel<<<nbA, 256, 0, stream>>>(counts, offsets, partials, N);
    scanB_kernel<<<1, 64, 0, stream>>>(partials, nbA);
    int nbC = (N + 255) / 256;
    scanC_kernel<<<nbC, 256, 0, stream>>>(offsets, cursor, partials, N, E);

    fill_kernel<<<egrid, block, 0, stream>>>(ei, cursor, srcs, E);

    int rgrid = (N + NODES_PER_BLOCK - 1) / NODES_PER_BLOCK;
    reduce_kernel<<<rgrid, block, 0, stream>>>(q, k, v, offsets, srcs, out, N);
}

// Round 4
// 141.595 us; speedup vs baseline: 3.1800x; 1.5770x over previous
//
#include <hip/hip_runtime.h>

#define HEADS 8
#define HID 128
#define NPB 4   // nodes per 256-thread block (1 wave each)

typedef unsigned short u16;
typedef unsigned int u32;

__device__ __forceinline__ float bf2f(u16 u) { return __uint_as_float(((u32)u) << 16); }
__device__ __forceinline__ u16 f2bf(float f) {
    u32 x = __float_as_uint(f);
    u32 r = (x + 0x7FFF + ((x >> 16) & 1)) >> 16;  // round-to-nearest-even
    return (u16)r;
}

// ---- fused pack (k*0.25,v -> bf16 interleaved rows) + count (+edge rank) ----
__global__ void pack_count_kernel(const float* __restrict__ k, const float* __restrict__ v,
                                  const int* __restrict__ ei, u16* __restrict__ kv,
                                  int* __restrict__ counts, int* __restrict__ pos,
                                  int N, int E, int packBlocks) {
    if ((int)blockIdx.x < packBlocks) {
        int g = blockIdx.x * 256 + threadIdx.x;   // node*64 + lane
        int node = g >> 6, l = g & 63;
        if (node < N) {
            float2 kk = ((const float2*)(k + (long long)node * HID))[l];
            float2 vv = ((const float2*)(v + (long long)node * HID))[l];
            ushort4 o;
            o.x = f2bf(kk.x * 0.25f);  // fold 1/SCALE (exact pow2) into k
            o.y = f2bf(kk.y * 0.25f);
            o.z = f2bf(vv.x);
            o.w = f2bf(vv.y);
            ((ushort4*)(kv + (long long)node * 256))[l] = o;
        }
    } else {
        int e = (blockIdx.x - packBlocks) * 256 + threadIdx.x;
        if (e < E) pos[e] = atomicAdd(&counts[ei[E + e]], 1);
    }
}

// ---- scan phase A: per-block (2048) local exclusive scan + block totals ----
__global__ void scanA_kernel(const int* __restrict__ counts, int* __restrict__ offsets,
                             int* __restrict__ partials, int N) {
    __shared__ int sdata[256];
    int tid = threadIdx.x;
    int base = blockIdx.x * 2048 + tid * 8;
    int v[8];
    int tsum = 0;
    for (int j = 0; j < 8; j++) {
        int idx = base + j;
        v[j] = (idx < N) ? counts[idx] : 0;
        tsum += v[j];
    }
    sdata[tid] = tsum;
    __syncthreads();
    for (int off = 1; off < 256; off <<= 1) {
        int x = sdata[tid];
        int y = (tid >= off) ? sdata[tid - off] : 0;
        __syncthreads();
        sdata[tid] = x + y;
        __syncthreads();
    }
    int excl = sdata[tid] - tsum;
    for (int j = 0; j < 8; j++) {
        int idx = base + j;
        if (idx < N) offsets[idx] = excl;
        excl += v[j];
    }
    if (tid == 255) partials[blockIdx.x] = sdata[255];
}

// ---- scan phase C (B fused): add scanned block base ----
__global__ void scanC_kernel(int* __restrict__ offsets, const int* __restrict__ partials,
                             int N, int E, int nbA) {
    __shared__ int sp[64];
    int tid = threadIdx.x;
    if (tid == 0) {
        int run = 0;
        for (int i = 0; i < nbA; i++) { sp[i] = run; run += partials[i]; }
    }
    __syncthreads();
    int idx = blockIdx.x * blockDim.x + tid;
    if (idx < N) offsets[idx] += sp[idx >> 11];
    if (idx == 0) offsets[N] = E;
}

// ---- fill: atomic-free scatter using precomputed ranks ----
__global__ void fill_kernel(const int* __restrict__ ei, const int* __restrict__ offsets,
                            const int* __restrict__ pos, int* __restrict__ srcs, int E) {
    int e = blockIdx.x * blockDim.x + threadIdx.x;
    if (e < E) srcs[offsets[ei[E + e]] + pos[e]] = ei[e];
}

// ---- per-node reduction, packed bf16 kv rows (8B/lane/edge) ----
__global__ __launch_bounds__(256) void reduce_packed(
        const float* __restrict__ q, const u16* __restrict__ kv,
        const int* __restrict__ offsets, const int* __restrict__ srcs,
        float* __restrict__ out, int N) {
    int node = blockIdx.x * NPB + (threadIdx.x >> 6);
    if (node >= N) return;
    int l = threadIdx.x & 63;

    float2 qv = ((const float2*)(q + (long long)node * HID))[l];
    const ushort4* kv4 = (const ushort4*)kv;   // 64 ushort4 per node row
    float accx = 0.0f, accy = 0.0f, z = 0.0f;

    int beg = offsets[node];
    int end = offsets[node + 1];
    int i = beg;
    for (; i + 4 <= end; i += 4) {
        int s0 = srcs[i + 0], s1 = srcs[i + 1], s2 = srcs[i + 2], s3 = srcs[i + 3];
        ushort4 a0 = kv4[(long long)s0 * 64 + l];
        ushort4 a1 = kv4[(long long)s1 * 64 + l];
        ushort4 a2 = kv4[(long long)s2 * 64 + l];
        ushort4 a3 = kv4[(long long)s3 * 64 + l];

        float p0 = bf2f(a0.x) * qv.x + bf2f(a0.y) * qv.y;   // k already /4
        float p1 = bf2f(a1.x) * qv.x + bf2f(a1.y) * qv.y;
        float p2 = bf2f(a2.x) * qv.x + bf2f(a2.y) * qv.y;
        float p3 = bf2f(a3.x) * qv.x + bf2f(a3.y) * qv.y;

        p0 += __shfl_xor(p0, 1); p1 += __shfl_xor(p1, 1);
        p2 += __shfl_xor(p2, 1); p3 += __shfl_xor(p3, 1);
        p0 += __shfl_xor(p0, 2); p1 += __shfl_xor(p1, 2);
        p2 += __shfl_xor(p2, 2); p3 += __shfl_xor(p3, 2);
        p0 += __shfl_xor(p0, 4); p1 += __shfl_xor(p1, 4);
        p2 += __shfl_xor(p2, 4); p3 += __shfl_xor(p3, 4);

        float c0 = __expf(fminf(fmaxf(p0, -5.0f), 5.0f));
        float c1 = __expf(fminf(fmaxf(p1, -5.0f), 5.0f));
        float c2 = __expf(fminf(fmaxf(p2, -5.0f), 5.0f));
        float c3 = __expf(fminf(fmaxf(p3, -5.0f), 5.0f));

        accx += bf2f(a0.z) * c0 + bf2f(a1.z) * c1 + bf2f(a2.z) * c2 + bf2f(a3.z) * c3;
        accy += bf2f(a0.w) * c0 + bf2f(a1.w) * c1 + bf2f(a2.w) * c2 + bf2f(a3.w) * c3;
        z += c0 + c1 + c2 + c3;
    }
    for (; i < end; i++) {
        int s = srcs[i];
        ushort4 a = kv4[(long long)s * 64 + l];
        float p = bf2f(a.x) * qv.x + bf2f(a.y) * qv.y;
        p += __shfl_xor(p, 1);
        p += __shfl_xor(p, 2);
        p += __shfl_xor(p, 4);
        float c = __expf(fminf(fmaxf(p, -5.0f), 5.0f));
        accx += bf2f(a.z) * c;
        accy += bf2f(a.w) * c;
        z += c;
    }
    float inv = 1.0f / (z + 1e-6f);
    ((float2*)(out + (long long)node * HID))[l] = make_float2(accx * inv, accy * inv);
}

// ---- fallback reduction (fp32 gathers) if workspace too small for pack ----
__global__ __launch_bounds__(256) void reduce_f32(
        const float* __restrict__ q, const float* __restrict__ k,
        const float* __restrict__ v, const int* __restrict__ offsets,
        const int* __restrict__ srcs, float* __restrict__ out, int N) {
    int node = blockIdx.x * NPB + (threadIdx.x >> 6);
    if (node >= N) return;
    int l = threadIdx.x & 63;
    float2 qv = ((const float2*)(q + (long long)node * HID))[l];
    float accx = 0.0f, accy = 0.0f, z = 0.0f;
    int beg = offsets[node], end = offsets[node + 1];
    for (int i = beg; i < end; i++) {
        int s = srcs[i];
        float2 kk = ((const float2*)(k + (long long)s * HID))[l];
        float2 vv = ((const float2*)(v + (long long)s * HID))[l];
        float p = (kk.x * qv.x + kk.y * qv.y) * 0.25f;
        p += __shfl_xor(p, 1);
        p += __shfl_xor(p, 2);
        p += __shfl_xor(p, 4);
        float c = __expf(fminf(fmaxf(p, -5.0f), 5.0f));
        accx += vv.x * c; accy += vv.y * c; z += c;
    }
    float inv = 1.0f / (z + 1e-6f);
    ((float2*)(out + (long long)node * HID))[l] = make_float2(accx * inv, accy * inv);
}

extern "C" void kernel_launch(void* const* d_in, const int* in_sizes, int n_in,
                              void* d_out, int out_size, void* d_ws, size_t ws_size,
                              hipStream_t stream) {
    const float* q = (const float*)d_in[0];
    const float* k = (const float*)d_in[1];
    const float* v = (const float*)d_in[2];
    const int* ei = (const int*)d_in[3];
    float* out = (float*)d_out;

    int E = in_sizes[3] / 2;      // 800000
    int N = in_sizes[0] / HID;    // 50000

    int block = 256;
    int eblocks = (E + block - 1) / block;
    int nbA = (N + 2047) / 2048;
    int nblocksN = (N + 255) / 256;
    int rgrid = (N + NPB - 1) / NPB;

    // packed layout: kv[N*256 u16] | counts[N] | offsets[N+1] | partials[256] | pos[E] | srcs[E]
    size_t kv_bytes = (size_t)N * 256 * sizeof(u16);
    size_t need_packed = kv_bytes + ((size_t)N + (size_t)N + 1 + 256 + 2 * (size_t)E) * 4 + 64;

    if (ws_size >= need_packed) {
        u16* kv = (u16*)d_ws;
        int* counts = (int*)((char*)d_ws + kv_bytes);
        int* offsets = counts + N;
        int* partials = offsets + N + 1;
        int* pos = partials + 256;
        int* srcs = pos + E;

        hipMemsetAsync(counts, 0, (size_t)N * sizeof(int), stream);

        int packBlocks = (N * 64 + block - 1) / block;
        pack_count_kernel<<<packBlocks + eblocks, block, 0, stream>>>(
            k, v, ei, kv, counts, pos, N, E, packBlocks);
        scanA_kernel<<<nbA, block, 0, stream>>>(counts, offsets, partials, N);
        scanC_kernel<<<nblocksN, block, 0, stream>>>(offsets, partials, N, E, nbA);
        fill_kernel<<<eblocks, block, 0, stream>>>(ei, offsets, pos, srcs, E);
        reduce_packed<<<rgrid, block, 0, stream>>>(q, kv, offsets, srcs, out, N);
    } else {
        // fallback: counts[N] | offsets[N+1] | partials[256] | pos[E] | srcs[E]
        int* counts = (int*)d_ws;
        int* offsets = counts + N;
        int* partials = offsets + N + 1;
        int* pos = partials + 256;
        int* srcs = pos + E;

        hipMemsetAsync(counts, 0, (size_t)N * sizeof(int), stream);
        pack_count_kernel<<<eblocks, block, 0, stream>>>(
            k, v, ei, (u16*)nullptr, counts, pos, N, E, 0);
        scanA_kernel<<<nbA, block, 0, stream>>>(counts, offsets, partials, N);
        scanC_kernel<<<nblocksN, block, 0, stream>>>(offsets, partials, N, E, nbA);
        fill_kernel<<<eblocks, block, 0, stream>>>(ei, offsets, pos, srcs, E);
        reduce_f32<<<rgrid, block, 0, stream>>>(q, k, v, offsets, srcs, out, N);
    }
}